// Round 1
// baseline (52767.340 us; speedup 1.0000x reference)
//
#include <hip/hip_runtime.h>
#include <hip/hip_cooperative_groups.h>

namespace cg = cooperative_groups;

#define BB 128
#define TT 512
#define DD 256
#define HH 512

__device__ __forceinline__ float sig_(float x) { return 1.0f / (1.0f + __expf(-x)); }

#define FMA4(ACC, AV, WV)                     \
  do {                                        \
    ACC[0] = fmaf((AV), (WV).x, ACC[0]);      \
    ACC[1] = fmaf((AV), (WV).y, ACC[1]);      \
    ACC[2] = fmaf((AV), (WV).z, ACC[2]);      \
    ACC[3] = fmaf((AV), (WV).w, ACC[3]);      \
  } while (0)

// async 16B global -> LDS copy (fire-and-forget; completion tracked by vmcnt)
__device__ __forceinline__ void gld16(void* lds, const void* gp) {
  __builtin_amdgcn_global_load_lds(
      (const __attribute__((address_space(1))) void*)gp,
      (__attribute__((address_space(3))) void*)lds, 16, 0, 0);
}

// ---------------- projection GEMM: xp = x @ proj_w.T + proj_b ----------------
// M=65536, N=256, K=256. Tile [64x64], Kt=64, thread 4x4. (unchanged)
__global__ __launch_bounds__(256) void proj_kernel(const float* __restrict__ x,
                                                   const float* __restrict__ pw,
                                                   const float* __restrict__ pb,
                                                   float* __restrict__ xp) {
  __shared__ float At[64 * 68];  // [row][k], pitch 68
  __shared__ float Bt[64 * 68];  // [k][n],   pitch 68
  const int bm = blockIdx.x >> 2;
  const int bn = blockIdx.x & 3;
  const int tid = threadIdx.x;
  const int rg = tid >> 4;    // 0..15 -> 4 rows each
  const int cgi = tid & 15;   // 0..15 -> 4 cols each
  const int m0 = bm * 64, n0 = bn * 64;
  float acc[4][4] = {};
  for (int kt = 0; kt < 4; ++kt) {
    const int k0 = kt * 64;
    {  // stage A (row-major, rows are k-contiguous in global)
      const int r = tid >> 2, q = tid & 3;
      const float4* src = (const float4*)(x + (size_t)(m0 + r) * DD + k0 + q * 16);
      float4* dst = (float4*)&At[r * 68 + q * 16];
#pragma unroll
      for (int j = 0; j < 4; ++j) dst[j] = src[j];
    }
    {  // stage B transposed: Bt[k][n]
      const int n = tid & 63, kg = tid >> 6;
      const float4* src = (const float4*)(pw + (size_t)(n0 + n) * DD + k0 + kg * 16);
#pragma unroll
      for (int j = 0; j < 4; ++j) {
        float4 v = src[j];
        const int kk = kg * 16 + j * 4;
        Bt[(kk + 0) * 68 + n] = v.x;
        Bt[(kk + 1) * 68 + n] = v.y;
        Bt[(kk + 2) * 68 + n] = v.z;
        Bt[(kk + 3) * 68 + n] = v.w;
      }
    }
    __syncthreads();
#pragma unroll
    for (int k4 = 0; k4 < 64; k4 += 4) {
      float4 a[4], b[4];
#pragma unroll
      for (int j = 0; j < 4; ++j) a[j] = *(const float4*)&At[(rg * 4 + j) * 68 + k4];
#pragma unroll
      for (int j = 0; j < 4; ++j) b[j] = *(const float4*)&Bt[(k4 + j) * 68 + cgi * 4];
#pragma unroll
      for (int jr = 0; jr < 4; ++jr) {
        FMA4(acc[jr], a[jr].x, b[0]);
        FMA4(acc[jr], a[jr].y, b[1]);
        FMA4(acc[jr], a[jr].z, b[2]);
        FMA4(acc[jr], a[jr].w, b[3]);
      }
    }
    __syncthreads();
  }
  const float4 bias = *(const float4*)&pb[n0 + cgi * 4];
#pragma unroll
  for (int jr = 0; jr < 4; ++jr) {
    float4 o;
    o.x = acc[jr][0] + bias.x;
    o.y = acc[jr][1] + bias.y;
    o.z = acc[jr][2] + bias.z;
    o.w = acc[jr][3] + bias.w;
    *(float4*)&xp[(size_t)(m0 + rg * 4 + jr) * DD + n0 + cgi * 4] = o;
  }
}

// ---------------- persistent pipelined 2-layer LSTM, LDS-resident weights ---
// 256 blocks x 256 threads, cooperative, 1 block/CU (128 KB LDS).
// Role split: blocks 0..127 = layer0 step p; 128..255 = layer1 step p-1.
// Block tile: [128 rows x 4 cells x 4 gates]. Weight slice (16 gate-cols x K)
// lives in LDS for the whole kernel; only activations stream per phase,
// double-buffered via global_load_lds + counted vmcnt (loads in flight
// across raw s_barrier).
// Thread: 2 rows x 1 cell x 4 gates (8 acc), c-state in 2 registers.

#define WLDS 16384  // floats: 1024 k x 16 cols (L0 uses first 768 k)
#define ABUF 8192   // floats: 128 rows x 64 k per buffer

__global__ __launch_bounds__(256, 1) void lstm_kernel(
    const float* __restrict__ xp,
    const float* __restrict__ wx0, const float* __restrict__ bx0,
    const float* __restrict__ wh0, const float* __restrict__ bh0,
    const float* __restrict__ wx1, const float* __restrict__ bx1,
    const float* __restrict__ wh1, const float* __restrict__ bh1,
    float* __restrict__ h0buf, float* __restrict__ h1buf) {
  cg::grid_group grid = cg::this_grid();
  __shared__ float lds[WLDS + 2 * ABUF];  // 128 KB static
  float* __restrict__ Wl = lds;           // W slice, [k][col], pitch 16
  float* __restrict__ Ab = lds + WLDS;    // A tiles, 2 x [128 rows][64 k], swizzled

  const int bidx = blockIdx.x;
  const int role = bidx >> 7;   // 0: layer0, 1: layer1
  const int bj = bidx & 127;    // cell-slice: cells bj*4 .. bj*4+3
  const int tid = threadIdx.x;
  const int cell = tid & 3;
  const int rowg = tid >> 2;    // 0..63 -> rows rowg*2, rowg*2+1
  const int cell_g = bj * 4 + cell;

  // zero initial h state (ws is re-poisoned before every launch)
  for (int idx = bidx * 256 + tid; idx < 2 * BB * HH; idx += 256 * 256) {
    h0buf[idx] = 0.0f;
    h1buf[idx] = 0.0f;
  }

  const float* __restrict__ wx = role ? wx1 : wx0;
  const float* __restrict__ wh = role ? wh1 : wh0;
  const float* __restrict__ bxv = role ? bx1 : bx0;
  const float* __restrict__ bhv = role ? bh1 : bh0;
  const int KX = role ? HH : DD;       // K of the "x" operand
  const int nt = (KX + HH) >> 6;       // 12 (L0) or 16 (L1) K-tiles
  const int ntx = KX >> 6;             // 4 or 8 tiles come from x-source

  // ---- stage weight slice into LDS once: Wl[k*16 + (lc*4+g)] ----
  {
    const int col = tid & 15, part = tid >> 4;
    const int lc = col >> 2, g = col & 3;
    const int grow = g * HH + bj * 4 + lc;  // global gate row 0..2047
    const int span = (KX + HH) >> 4;        // 48 or 64 k per thread
    const int k0 = part * span;
    for (int k = k0; k < k0 + span; k += 4) {
      float4 v;
      if (k < KX) v = *(const float4*)(wx + (size_t)grow * KX + k);
      else        v = *(const float4*)(wh + (size_t)grow * HH + (k - KX));
      Wl[(k + 0) * 16 + col] = v.x;
      Wl[(k + 1) * 16 + col] = v.y;
      Wl[(k + 2) * 16 + col] = v.z;
      Wl[(k + 3) * 16 + col] = v.w;
    }
  }

  float bg[4];
#pragma unroll
  for (int g = 0; g < 4; ++g)
    bg[g] = bxv[(size_t)g * HH + cell_g] + bhv[(size_t)g * HH + cell_g];

  // ---- precompute staging offsets (constant all phases) ----
  // granule idx = j*256 + tid; row = j*16 + (tid>>4); kg = tid&15.
  // A LDS row r is XOR-swizzled on 16B granules by s(r) = (r>>1)&15 so a
  // wave's 16 distinct-row ds_read_b128s land on distinct bank groups.
  // global_load_lds writes linearly, so the swizzle is applied to the
  // GLOBAL source column (both-sides-or-neither rule).
  uint32_t xo[8], ho[8], lo[8];
  {
    const int kg = tid & 15, rb = tid >> 4;
    const size_t xstr = role ? (size_t)HH : (size_t)TT * DD;  // x-source row stride
#pragma unroll
    for (int j = 0; j < 8; ++j) {
      const int row = j * 16 + rb;
      const int cgj = kg ^ ((row >> 1) & 15);  // swizzled source granule
      xo[j] = (uint32_t)(((size_t)row * xstr + (size_t)cgj * 4) * 4);
      ho[j] = (uint32_t)(((size_t)row * HH + (size_t)cgj * 4) * 4);
      lo[j] = (uint32_t)((j * 256 + tid) * 16);  // linear LDS dest bytes
    }
  }
  const int sw = (rowg & 15) << 2;  // read-side swizzle (same for both rows)

  float cst0 = 0.0f, cst1 = 0.0f;

  __threadfence();
  grid.sync();

  for (int p = 0; p <= TT; ++p) {
    const bool active = role ? (p >= 1) : (p < TT);
    if (active) {
      const int t = role ? (p - 1) : p;
      const int rdbuf = (p + 1) & 1;  // written during phase p-1 (or zero-init)
      const int wrbuf = p & 1;
      const char* __restrict__ xs =
          role ? (const char*)(h0buf + (size_t)rdbuf * BB * HH)
               : (const char*)(xp + (size_t)t * DD);
      const char* __restrict__ hs =
          (const char*)((role ? h1buf : h0buf) + (size_t)rdbuf * BB * HH);
      float* __restrict__ hout = (role ? h1buf : h0buf) + (size_t)wrbuf * BB * HH;

      float acc0[4] = {0.f, 0.f, 0.f, 0.f};
      float acc1[4] = {0.f, 0.f, 0.f, 0.f};

      // prologue: tile 0 -> buf 0 (tile 0 is always from the x-source)
#pragma unroll
      for (int j = 0; j < 8; ++j) gld16((char*)Ab + lo[j], xs + xo[j]);

#pragma unroll 1
      for (int kt = 0; kt < nt; ++kt) {
        if (kt + 1 < nt) {
          // issue next tile's 8 loads into the other buffer, then wait for
          // the CURRENT tile's 8 (counted vmcnt: next tile stays in flight)
          const int kn = kt + 1;
          const bool inx = kn < ntx;
          const char* b = inx ? (xs + (size_t)kn * 256)
                              : (hs + (size_t)(kn - ntx) * 256);
          char* l = (char*)Ab + ((kn & 1) ? (ABUF * 4) : 0);
#pragma unroll
          for (int j = 0; j < 8; ++j) gld16(l + lo[j], b + (inx ? xo[j] : ho[j]));
          asm volatile("s_waitcnt vmcnt(8)" ::: "memory");
        } else {
          asm volatile("s_waitcnt vmcnt(0)" ::: "memory");
        }
        __builtin_amdgcn_s_barrier();          // raw barrier: no vmcnt(0) drain
        asm volatile("" ::: "memory");         // pin LDS reads below barrier
        const float* __restrict__ Wt = Wl + (kt << 10) + (cell << 2);
        const float* __restrict__ Ar = Ab + ((kt & 1) ? ABUF : 0) + rowg * 128;
#pragma unroll
        for (int k4 = 0; k4 < 64; k4 += 4) {
          const int kk = k4 ^ sw;
          const float4 a0 = *(const float4*)(Ar + kk);        // row rowg*2
          const float4 a1 = *(const float4*)(Ar + 64 + kk);   // row rowg*2+1
          const float* wp = Wt + (k4 << 4);
          const float4 w0 = *(const float4*)(wp + 0);   // gates i,f,g,o @ k4+0
          const float4 w1 = *(const float4*)(wp + 16);
          const float4 w2 = *(const float4*)(wp + 32);
          const float4 w3 = *(const float4*)(wp + 48);
          FMA4(acc0, a0.x, w0);
          FMA4(acc0, a0.y, w1);
          FMA4(acc0, a0.z, w2);
          FMA4(acc0, a0.w, w3);
          FMA4(acc1, a1.x, w0);
          FMA4(acc1, a1.y, w1);
          FMA4(acc1, a1.z, w2);
          FMA4(acc1, a1.w, w3);
        }
        __builtin_amdgcn_s_barrier();  // all waves done reading buf[kt&1]
      }

      // ---- cell update + h store ----
      {
        float iv = acc0[0] + bg[0], fv = acc0[1] + bg[1];
        float gv = acc0[2] + bg[2], ov = acc0[3] + bg[3];
        float cn = sig_(fv) * cst0 + sig_(iv) * tanhf(gv);
        cst0 = cn;
        hout[(size_t)(rowg * 2 + 0) * HH + cell_g] = sig_(ov) * tanhf(cn);
        iv = acc1[0] + bg[0]; fv = acc1[1] + bg[1];
        gv = acc1[2] + bg[2]; ov = acc1[3] + bg[3];
        cn = sig_(fv) * cst1 + sig_(iv) * tanhf(gv);
        cst1 = cn;
        hout[(size_t)(rowg * 2 + 1) * HH + cell_g] = sig_(ov) * tanhf(cn);
      }
    }
    __threadfence();
    grid.sync();
  }
}

// ---------------- head: out = relu(h1 @ fc1.T + b1) @ fc2.T + b2 ------------
__global__ __launch_bounds__(256) void head_kernel(const float* __restrict__ h1,
                                                   const float* __restrict__ fc1w,
                                                   const float* __restrict__ fc1b,
                                                   const float* __restrict__ fc2w,
                                                   const float* __restrict__ fc2b,
                                                   float* __restrict__ out) {
  __shared__ float part[256];
  __shared__ float hid[32];
  const int r = blockIdx.x;
  const int tid = threadIdx.x;
  const int c = tid & 31, pt = tid >> 5;  // 32 cols x 8 K-parts
  const float4* ha = (const float4*)(h1 + (size_t)r * HH + pt * 64);
  const float4* wa = (const float4*)(fc1w + (size_t)c * HH + pt * 64);
  float s = 0.f;
#pragma unroll
  for (int j = 0; j < 16; ++j) {
    float4 av = ha[j], wv = wa[j];
    s = fmaf(av.x, wv.x, s);
    s = fmaf(av.y, wv.y, s);
    s = fmaf(av.z, wv.z, s);
    s = fmaf(av.w, wv.w, s);
  }
  part[tid] = s;
  __syncthreads();
  if (tid < 32) {
    float v = fc1b[tid];
#pragma unroll
    for (int q = 0; q < 8; ++q) v += part[q * 32 + tid];
    hid[tid] = fmaxf(v, 0.f);
  }
  __syncthreads();
  if (tid == 0) {
    float v = fc2b[0];
    for (int cc = 0; cc < 32; ++cc) v = fmaf(hid[cc], fc2w[cc], v);
    out[r] = v;
  }
}

extern "C" void kernel_launch(void* const* d_in, const int* in_sizes, int n_in,
                              void* d_out, int out_size, void* d_ws, size_t ws_size,
                              hipStream_t stream) {
  const float* x    = (const float*)d_in[0];
  const float* pw   = (const float*)d_in[1];
  const float* pb   = (const float*)d_in[2];
  const float* wx0  = (const float*)d_in[3];
  const float* bx0  = (const float*)d_in[4];
  const float* wh0  = (const float*)d_in[5];
  const float* bh0  = (const float*)d_in[6];
  const float* wx1  = (const float*)d_in[7];
  const float* bx1  = (const float*)d_in[8];
  const float* wh1  = (const float*)d_in[9];
  const float* bh1  = (const float*)d_in[10];
  const float* fc1w = (const float*)d_in[11];
  const float* fc1b = (const float*)d_in[12];
  const float* fc2w = (const float*)d_in[13];
  const float* fc2b = (const float*)d_in[14];
  float* out = (float*)d_out;

  // workspace layout (floats): xp [B*T*D] | h0buf [2*B*H] | h1buf [2*B*H]
  float* xp = (float*)d_ws;
  float* h0buf = xp + (size_t)BB * TT * DD;
  float* h1buf = h0buf + 2 * BB * HH;

  proj_kernel<<<dim3(4096), dim3(256), 0, stream>>>(x, pw, pb, xp);

  void* kargs[] = {(void*)&xp,  (void*)&wx0, (void*)&bx0, (void*)&wh0,
                   (void*)&bh0, (void*)&wx1, (void*)&bx1, (void*)&wh1,
                   (void*)&bh1, (void*)&h0buf, (void*)&h1buf};
  hipLaunchCooperativeKernel((void*)lstm_kernel, dim3(256), dim3(256), kargs, 0,
                             stream);

  // final h1 lives in buffer index (512 & 1) == 0
  head_kernel<<<dim3(BB), dim3(256), 0, stream>>>(h1buf, fc1w, fc1b, fc2w, fc2b, out);
}

// Round 8
// 36436.206 us; speedup vs baseline: 1.4482x; 1.4482x over previous
//
#include <hip/hip_runtime.h>

#define BB 128
#define TT 512
#define DD 256
#define HH 512

__device__ __forceinline__ float sig_(float x) { return 1.0f / (1.0f + __expf(-x)); }

#define FMA4(ACC, AV, WV)                     \
  do {                                        \
    ACC[0] = fmaf((AV), (WV).x, ACC[0]);      \
    ACC[1] = fmaf((AV), (WV).y, ACC[1]);      \
    ACC[2] = fmaf((AV), (WV).z, ACC[2]);      \
    ACC[3] = fmaf((AV), (WV).w, ACC[3]);      \
  } while (0)

// Persistent c-state across per-phase launches. Block-private (each block
// owns its [role][rows][4 cells] slice; each THREAD owns its 2 elements),
// so plain loads/stores + kernel-boundary ordering are sufficient.
// 2*128*512 floats = 512 KB, compiler-allocated (zero ws growth).
// Re-initialized by the first==true branch every sequence (idempotent
// across harness re-runs).
__device__ float g_c[2 * BB * HH];

// ---------------- projection GEMM: xp = x @ proj_w.T + proj_b ----------------
// (unchanged, known-good)
__global__ __launch_bounds__(256) void proj_kernel(const float* __restrict__ x,
                                                   const float* __restrict__ pw,
                                                   const float* __restrict__ pb,
                                                   float* __restrict__ xp) {
  __shared__ float At[64 * 68];
  __shared__ float Bt[64 * 68];
  const int bm = blockIdx.x >> 2;
  const int bn = blockIdx.x & 3;
  const int tid = threadIdx.x;
  const int rg = tid >> 4;
  const int cgi = tid & 15;
  const int m0 = bm * 64, n0 = bn * 64;
  float acc[4][4] = {};
  for (int kt = 0; kt < 4; ++kt) {
    const int k0 = kt * 64;
    {
      const int r = tid >> 2, q = tid & 3;
      const float4* src = (const float4*)(x + (size_t)(m0 + r) * DD + k0 + q * 16);
      float4* dst = (float4*)&At[r * 68 + q * 16];
#pragma unroll
      for (int j = 0; j < 4; ++j) dst[j] = src[j];
    }
    {
      const int n = tid & 63, kg = tid >> 6;
      const float4* src = (const float4*)(pw + (size_t)(n0 + n) * DD + k0 + kg * 16);
#pragma unroll
      for (int j = 0; j < 4; ++j) {
        float4 v = src[j];
        const int kk = kg * 16 + j * 4;
        Bt[(kk + 0) * 68 + n] = v.x;
        Bt[(kk + 1) * 68 + n] = v.y;
        Bt[(kk + 2) * 68 + n] = v.z;
        Bt[(kk + 3) * 68 + n] = v.w;
      }
    }
    __syncthreads();
#pragma unroll
    for (int k4 = 0; k4 < 64; k4 += 4) {
      float4 a[4], b[4];
#pragma unroll
      for (int j = 0; j < 4; ++j) a[j] = *(const float4*)&At[(rg * 4 + j) * 68 + k4];
#pragma unroll
      for (int j = 0; j < 4; ++j) b[j] = *(const float4*)&Bt[(k4 + j) * 68 + cgi * 4];
#pragma unroll
      for (int jr = 0; jr < 4; ++jr) {
        FMA4(acc[jr], a[jr].x, b[0]);
        FMA4(acc[jr], a[jr].y, b[1]);
        FMA4(acc[jr], a[jr].z, b[2]);
        FMA4(acc[jr], a[jr].w, b[3]);
      }
    }
    __syncthreads();
  }
  const float4 bias = *(const float4*)&pb[n0 + cgi * 4];
#pragma unroll
  for (int jr = 0; jr < 4; ++jr) {
    float4 o;
    o.x = acc[jr][0] + bias.x;
    o.y = acc[jr][1] + bias.y;
    o.z = acc[jr][2] + bias.z;
    o.w = acc[jr][3] + bias.w;
    *(float4*)&xp[(size_t)(m0 + rg * 4 + jr) * DD + n0 + cgi * 4] = o;
  }
}

// ---------------- per-phase 2-layer LSTM step -------------------------------
// ONE LAUNCH PER PHASE (513 total, graph-captured). Kernel boundaries provide
// the grid-wide barrier + coherence — no cooperative launch, no atomics, no
// fences, no spins. Grid 256 blocks x 256 threads, 1 block/CU (128 KB LDS).
// Blocks 0..127: layer0 step p; blocks 128..255: layer1 step p-1.
// Block tile: [128 rows x 4 cells x 4 gates]; thread: 2 rows x 1 cell.
// W slice (16 gate-cols x K) staged to LDS per launch (L2-resident, ~64 KB).

// --- A-tile reg staging: 8 x float4 per thread (128 rows x 64 k per tile) ---
__device__ __forceinline__ void load_plain(float4 (&R)[8], const float* base,
                                           size_t rs, int trb, int gq) {
#pragma unroll
  for (int j = 0; j < 8; ++j)
    R[j] = *(const float4*)(base + (size_t)(j * 16 + trb) * rs + (gq << 2));
}

// LDS A layout: row r, granule g stored at r*64 + (g ^ ((r>>1)&7))*4.
__device__ __forceinline__ void write_tile(float* Abuf, const float4 (&R)[8],
                                           int trb, int wp_) {
#pragma unroll
  for (int j = 0; j < 8; ++j)
    *(float4*)&Abuf[(j * 16 + trb) * 64 + (wp_ << 2)] = R[j];
}

__device__ __forceinline__ void compute_tile(float acc0[4], float acc1[4],
                                             const float* Abuf, const float* Wl,
                                             int kt, int rowg, int cell) {
  const float* Wt = Wl + (kt << 10) + (cell << 2);
  const float* Ar = Abuf + rowg * 128;
  const int rsw = rowg & 7;
#pragma unroll
  for (int k4 = 0; k4 < 64; k4 += 4) {
    const int off = (((k4 >> 2) ^ rsw) << 2);
    const float4 a0 = *(const float4*)(Ar + off);        // row 2*rowg
    const float4 a1 = *(const float4*)(Ar + 64 + off);   // row 2*rowg+1
    const float* wp = Wt + (k4 << 4);
    const float4 w0 = *(const float4*)(wp + 0);
    const float4 w1 = *(const float4*)(wp + 16);
    const float4 w2 = *(const float4*)(wp + 32);
    const float4 w3 = *(const float4*)(wp + 48);
    FMA4(acc0, a0.x, w0);
    FMA4(acc0, a0.y, w1);
    FMA4(acc0, a0.z, w2);
    FMA4(acc0, a0.w, w3);
    FMA4(acc1, a1.x, w0);
    FMA4(acc1, a1.y, w1);
    FMA4(acc1, a1.z, w2);
    FMA4(acc1, a1.w, w3);
  }
}

__global__ __launch_bounds__(256, 1) void lstm_phase(
    const float* __restrict__ xp,
    const float* __restrict__ wx0, const float* __restrict__ bx0,
    const float* __restrict__ wh0, const float* __restrict__ bh0,
    const float* __restrict__ wx1, const float* __restrict__ bx1,
    const float* __restrict__ wh1, const float* __restrict__ bh1,
    float* __restrict__ h0buf, float* __restrict__ h1buf, int p) {
  __shared__ float Wl[16384];    // W slice [k][16 cols], pitch 16 (64 KB)
  __shared__ float Ab[2][8192];  // A tiles, swizzled (2 x 32 KB)

  const int bidx = blockIdx.x;
  const int role = bidx >> 7;  // 0: layer0, 1: layer1
  const bool active = role ? (p >= 1) : (p < TT);
  if (!active) return;

  const int bj = bidx & 127;   // cell-slice: cells bj*4 .. bj*4+3
  const int tid = threadIdx.x;
  const int cell = tid & 3;
  const int rowg = tid >> 2;   // rows rowg*2, rowg*2+1
  const int trb = tid >> 4;    // staging row base
  const int gq = tid & 15;     // staging granule
  const int wp_ = gq ^ ((trb >> 1) & 7);  // swizzled write position
  const int cell_g = bj * 4 + cell;

  const float* __restrict__ wx = role ? wx1 : wx0;
  const float* __restrict__ wh = role ? wh1 : wh0;
  const float* __restrict__ bxv = role ? bx1 : bx0;
  const float* __restrict__ bhv = role ? bh1 : bh0;
  const int KX = role ? HH : DD;   // K of the "x" operand
  const int nt = (KX + HH) >> 6;   // 12 (L0) or 16 (L1) K-tiles

  // ---- stage weight slice into LDS: Wl[k*16 + (lc*4+g)] ----
  {
    const int col = tid & 15, part = tid >> 4;
    const int lc = col >> 2, g = col & 3;
    const int grow = g * HH + bj * 4 + lc;  // global gate row 0..2047
    const int span = (KX + HH) >> 4;        // 48 or 64 k per thread
    const int k0 = part * span;
    for (int k = k0; k < k0 + span; k += 4) {
      float4 v;
      if (k < KX) v = *(const float4*)(wx + (size_t)grow * KX + k);
      else        v = *(const float4*)(wh + (size_t)grow * HH + (k - KX));
      Wl[(k + 0) * 16 + col] = v.x;
      Wl[(k + 1) * 16 + col] = v.y;
      Wl[(k + 2) * 16 + col] = v.z;
      Wl[(k + 3) * 16 + col] = v.w;
    }
  }

  float bg[4];
#pragma unroll
  for (int g = 0; g < 4; ++g)
    bg[g] = bxv[(size_t)g * HH + cell_g] + bhv[(size_t)g * HH + cell_g];

  const int t = role ? (p - 1) : p;
  const int rd = (p + 1) & 1;  // buffer written during phase p-1
  const int wr = p & 1;
  const float* __restrict__ h0rd = h0buf + (size_t)rd * BB * HH;
  const float* __restrict__ h1rd = h1buf + (size_t)rd * BB * HH;
  float* __restrict__ hout = (role ? h1buf : h0buf) + (size_t)wr * BB * HH;

  // c-state: first step of this layer starts from 0 (re-inits every sequence)
  const bool first = role ? (p == 1) : (p == 0);
  float* __restrict__ cslot0 = &g_c[((size_t)role * BB + rowg * 2 + 0) * HH + cell_g];
  float* __restrict__ cslot1 = &g_c[((size_t)role * BB + rowg * 2 + 1) * HH + cell_g];
  const float cst0 = first ? 0.0f : *cslot0;
  const float cst1 = first ? 0.0f : *cslot1;

  float acc0[4] = {0.f, 0.f, 0.f, 0.f};
  float acc1[4] = {0.f, 0.f, 0.f, 0.f};

  auto srcload = [&](float4(&R)[8], int kt) {
    if (role == 0) {
      if (kt < 4)
        load_plain(R, xp + (size_t)t * DD + kt * 64, (size_t)TT * DD, trb, gq);
      else
        load_plain(R, h0rd + (kt - 4) * 64, (size_t)HH, trb, gq);
    } else {
      if (kt < 8) load_plain(R, h0rd + kt * 64, (size_t)HH, trb, gq);
      else        load_plain(R, h1rd + (kt - 8) * 64, (size_t)HH, trb, gq);
    }
  };

  float4 ra[8], rb4[8];
  srcload(ra, 0);
  __syncthreads();  // Wl staged (also covers Ab reuse below)
#pragma unroll 1
  for (int kt = 0; kt < nt; kt += 2) {  // nt is even (12 or 16)
    srcload(rb4, kt + 1);
    write_tile(Ab[0], ra, trb, wp_);
    __syncthreads();
    compute_tile(acc0, acc1, Ab[0], Wl, kt, rowg, cell);
    if (kt + 2 < nt) srcload(ra, kt + 2);
    __syncthreads();                 // buf0 readers done
    write_tile(Ab[1], rb4, trb, wp_);
    __syncthreads();
    compute_tile(acc0, acc1, Ab[1], Wl, kt + 1, rowg, cell);
    __syncthreads();                 // buf1 readers done (before next write)
  }

  // ---- cell update + h store (plain; kernel boundary publishes) ----
  {
    float iv = acc0[0] + bg[0], fv = acc0[1] + bg[1];
    float gv = acc0[2] + bg[2], ov = acc0[3] + bg[3];
    float cn = sig_(fv) * cst0 + sig_(iv) * tanhf(gv);
    *cslot0 = cn;
    hout[(size_t)(rowg * 2 + 0) * HH + cell_g] = sig_(ov) * tanhf(cn);
    iv = acc1[0] + bg[0]; fv = acc1[1] + bg[1];
    gv = acc1[2] + bg[2]; ov = acc1[3] + bg[3];
    cn = sig_(fv) * cst1 + sig_(iv) * tanhf(gv);
    *cslot1 = cn;
    hout[(size_t)(rowg * 2 + 1) * HH + cell_g] = sig_(ov) * tanhf(cn);
  }
}

// ---------------- head: out = relu(h1 @ fc1.T + b1) @ fc2.T + b2 ------------
__global__ __launch_bounds__(256) void head_kernel(const float* __restrict__ h1,
                                                   const float* __restrict__ fc1w,
                                                   const float* __restrict__ fc1b,
                                                   const float* __restrict__ fc2w,
                                                   const float* __restrict__ fc2b,
                                                   float* __restrict__ out) {
  __shared__ float part[256];
  __shared__ float hid[32];
  const int r = blockIdx.x;
  const int tid = threadIdx.x;
  const int c = tid & 31, pt = tid >> 5;
  const float4* ha = (const float4*)(h1 + (size_t)r * HH + pt * 64);
  const float4* wa = (const float4*)(fc1w + (size_t)c * HH + pt * 64);
  float s = 0.f;
#pragma unroll
  for (int j = 0; j < 16; ++j) {
    float4 av = ha[j], wv = wa[j];
    s = fmaf(av.x, wv.x, s);
    s = fmaf(av.y, wv.y, s);
    s = fmaf(av.z, wv.z, s);
    s = fmaf(av.w, wv.w, s);
  }
  part[tid] = s;
  __syncthreads();
  if (tid < 32) {
    float v = fc1b[tid];
#pragma unroll
    for (int q = 0; q < 8; ++q) v += part[q * 32 + tid];
    hid[tid] = fmaxf(v, 0.f);
  }
  __syncthreads();
  if (tid == 0) {
    float v = fc2b[0];
    for (int cc = 0; cc < 32; ++cc) v = fmaf(hid[cc], fc2w[cc], v);
    out[r] = v;
  }
}

extern "C" void kernel_launch(void* const* d_in, const int* in_sizes, int n_in,
                              void* d_out, int out_size, void* d_ws, size_t ws_size,
                              hipStream_t stream) {
  const float* x    = (const float*)d_in[0];
  const float* pw   = (const float*)d_in[1];
  const float* pb   = (const float*)d_in[2];
  const float* wx0  = (const float*)d_in[3];
  const float* bx0  = (const float*)d_in[4];
  const float* wh0  = (const float*)d_in[5];
  const float* bh0  = (const float*)d_in[6];
  const float* wx1  = (const float*)d_in[7];
  const float* bx1  = (const float*)d_in[8];
  const float* wh1  = (const float*)d_in[9];
  const float* bh1  = (const float*)d_in[10];
  const float* fc1w = (const float*)d_in[11];
  const float* fc1b = (const float*)d_in[12];
  const float* fc2w = (const float*)d_in[13];
  const float* fc2b = (const float*)d_in[14];
  float* out = (float*)d_out;

  // ws layout (floats): xp [B*T*D] | h0buf [2*B*H] | h1buf [2*B*H]
  // — EXACTLY the round-0/1 proven footprint, nothing appended.
  float* xp = (float*)d_ws;
  float* h0buf = xp + (size_t)BB * TT * DD;
  float* h1buf = h0buf + 2 * BB * HH;

  // zero initial h state (both buffers, both slots; 1 MB, stream-ordered)
  hipMemsetAsync(h0buf, 0, (size_t)4 * BB * HH * sizeof(float), stream);

  proj_kernel<<<dim3(4096), dim3(256), 0, stream>>>(x, pw, pb, xp);

  // 513 per-phase launches: kernel boundaries = grid barrier + coherence.
  for (int p = 0; p <= TT; ++p) {
    lstm_phase<<<dim3(256), dim3(256), 0, stream>>>(
        xp, wx0, bx0, wh0, bh0, wx1, bx1, wh1, bh1, h0buf, h1buf, p);
  }

  // final h1 lives in buffer index (512 & 1) == 0
  head_kernel<<<dim3(BB), dim3(256), 0, stream>>>(h1buf, fc1w, fc1b, fc2w, fc2b, out);
}